// Round 7
// baseline (657.598 us; speedup 1.0000x reference)
//
#include <hip/hip_runtime.h>
#include <hip/hip_fp16.h>

#define N_NODES 100000
#define N_EDGES 1600000
#define N_REL 4

// ---------------------------------------------------------------------------
// fp32 -> fp16 table conversion (x4 vectorized)
// ---------------------------------------------------------------------------
__global__ __launch_bounds__(256) void cvt_kernel(const float* __restrict__ in,
                                                  __half* __restrict__ out,
                                                  int n4) {
  int i = blockIdx.x * 256 + threadIdx.x;
  if (i >= n4) return;
  float4 v = ((const float4*)in)[i];
  __half2* o = (__half2*)(out + (long)i * 4);
  o[0] = __floats2half2_rn(v.x, v.y);
  o[1] = __floats2half2_rn(v.z, v.w);
}

// ---------------------------------------------------------------------------
// CSR build: count -> alloc (block scan + bump pointer) -> fill
// ---------------------------------------------------------------------------
__global__ __launch_bounds__(256) void count_kernel(const int* __restrict__ dst,
                                                    const int* __restrict__ et,
                                                    int* __restrict__ cnt,
                                                    int E, int N) {
  int e = blockIdx.x * 256 + threadIdx.x;
  if (e >= E) return;
  atomicAdd(&cnt[et[e] * N + dst[e]], 1);
}

__global__ __launch_bounds__(256) void alloc_kernel(const int* __restrict__ cnt,
                                                    int* __restrict__ off,
                                                    int* __restrict__ cur,
                                                    int* __restrict__ top,
                                                    int RN) {
  __shared__ int s[256];
  __shared__ int base;
  const int i = blockIdx.x * 256 + threadIdx.x;
  const int c = (i < RN) ? cnt[i] : 0;
  s[threadIdx.x] = c;
  __syncthreads();
  for (int d = 1; d < 256; d <<= 1) {
    int v = (threadIdx.x >= d) ? s[threadIdx.x - d] : 0;
    __syncthreads();
    s[threadIdx.x] += v;
    __syncthreads();
  }
  if (threadIdx.x == 255) base = atomicAdd(top, s[255]);
  __syncthreads();
  if (i < RN) {
    int excl = base + s[threadIdx.x] - c;
    off[i] = excl;
    cur[i] = excl;
  }
}

__global__ __launch_bounds__(256) void fill_kernel(
    const int* __restrict__ src, const int* __restrict__ dst,
    const int* __restrict__ et, int* __restrict__ cur, int* __restrict__ eidx,
    int E, int N) {
  int e = blockIdx.x * 256 + threadIdx.x;
  if (e >= E) return;
  int seg = et[e] * N + dst[e];
  int pos = atomicAdd(&cur[seg], 1);
  eidx[pos] = src[e];
}

// ---------------------------------------------------------------------------
// Expand: xe[p][16 halves] = tab[eidx[p]][16 halves].
// One thread per (edge, 16B granule). Pure gather (L2-resident 3.2 MB table)
// + perfectly coalesced streaming write. No loops, no dependent chains.
// ---------------------------------------------------------------------------
__global__ __launch_bounds__(256) void expand_kernel(
    const __half* __restrict__ tab, const int* __restrict__ eidx,
    __half* __restrict__ xe, int E) {
  int t = blockIdx.x * 256 + threadIdx.x;
  if (t >= 2 * E) return;
  int p = t >> 1;
  int g = t & 1;
  int idx = eidx[p];
  ((float4*)xe)[t] = ((const float4*)tab)[((long)idx << 1) | g];
}

// ---------------------------------------------------------------------------
// Reduce: segment-mean over contiguous xe + dense transform, all DIN=16.
//   acc = bias + self@root_half + sum_r mean_r @ W_half_r  (+prev out if ACCUM)
// Phase 1: thread=(node,r,granule g in {0,1}); reads xe rows CONTIGUOUSLY
//   (float4, 4-deep unrolled streaming), mean -> LDS.
// Phase 2: thread=(node,oc); W/root from global (L1-resident broadcast).
// SPLIT_OUT: write halves to outA/outB (fp16) for channel-split h2.
// ---------------------------------------------------------------------------
template <int DOUT, bool RELU, bool ACCUM, bool SPLIT_OUT, bool OUT_HALF>
__global__ __launch_bounds__(256, 8) void reduce_kernel(
    const __half* __restrict__ tab,  // self table [N][16] (this half)
    const __half* __restrict__ xe,   // expanded [E][16]
    const int* __restrict__ cnt, const int* __restrict__ off,
    const float* __restrict__ W, int relStride,  // W rows for this half
    const float* __restrict__ root,              // root rows for this half
    const float* __restrict__ bias,              // null on ACCUM pass
    void* __restrict__ outA, void* __restrict__ outB, int N) {
  constexpr int GN = 32;  // nodes per block (256 / (4 rel * 2 granules))
  __shared__ float sAgg[GN][N_REL][16];
  __shared__ float sX[GN][16];

  // ---- phase 1: streaming segment mean ----
  {
    const int g = threadIdx.x & 1;
    const int r = (threadIdx.x >> 1) & 3;
    const int ni = threadIdx.x >> 3;
    const int node = blockIdx.x * GN + ni;
    if (node < N) {
      if (r == 0) {  // stage self row
        union { float4 f; __half2 h[4]; } u;
        u.f = ((const float4*)tab)[((long)node << 1) | g];
        float* d = &sX[ni][g * 8];
#pragma unroll
        for (int k = 0; k < 4; k++) {
          float2 f2 = __half22float2(u.h[k]);
          d[2 * k] = f2.x;
          d[2 * k + 1] = f2.y;
        }
      }
      const int seg = r * N + node;
      const int c = cnt[seg];
      const long st = off[seg];
      const float4* base = (const float4*)xe + (st << 1) + g;  // stride 2/edge
      float s[8] = {0.f, 0.f, 0.f, 0.f, 0.f, 0.f, 0.f, 0.f};
      int e = 0;
      for (; e + 4 <= c; e += 4) {  // 4 independent streaming loads in flight
        union { float4 f; __half2 h[4]; } u0, u1, u2, u3;
        u0.f = base[2 * (e + 0)];
        u1.f = base[2 * (e + 1)];
        u2.f = base[2 * (e + 2)];
        u3.f = base[2 * (e + 3)];
#pragma unroll
        for (int k = 0; k < 4; k++) {
          float2 a = __half22float2(u0.h[k]);
          float2 b = __half22float2(u1.h[k]);
          float2 cc = __half22float2(u2.h[k]);
          float2 dd = __half22float2(u3.h[k]);
          s[2 * k] += (a.x + b.x) + (cc.x + dd.x);
          s[2 * k + 1] += (a.y + b.y) + (cc.y + dd.y);
        }
      }
      for (; e < c; e++) {
        union { float4 f; __half2 h[4]; } u0;
        u0.f = base[2 * e];
#pragma unroll
        for (int k = 0; k < 4; k++) {
          float2 a = __half22float2(u0.h[k]);
          s[2 * k] += a.x;
          s[2 * k + 1] += a.y;
        }
      }
      const float ic = (c > 0) ? 1.f / (float)c : 0.f;
      float* d = &sAgg[ni][r][g * 8];
#pragma unroll
      for (int k = 0; k < 8; k++) d[k] = s[k] * ic;
    }
  }
  __syncthreads();

  // ---- phase 2: dense transform ----
  constexpr int NPP = 256 / DOUT;
  constexpr int PASSES = GN / NPP;
  const int oc = threadIdx.x % DOUT;
  const int nj0 = threadIdx.x / DOUT;
#pragma unroll
  for (int p = 0; p < PASSES; p++) {
    const int nj = nj0 + p * NPP;
    const int node2 = blockIdx.x * GN + nj;
    if (node2 < N) {
      float acc = ACCUM ? ((const float*)outA)[(long)node2 * DOUT + oc]
                        : bias[oc];
#pragma unroll
      for (int k = 0; k < 16; k++) acc += sX[nj][k] * root[k * DOUT + oc];
#pragma unroll
      for (int r = 0; r < N_REL; r++) {
#pragma unroll
        for (int k = 0; k < 16; k++)
          acc += sAgg[nj][r][k] * W[r * relStride + k * DOUT + oc];
      }
      if (RELU) acc = fmaxf(acc, 0.f);
      if (SPLIT_OUT) {
        __half hv = __float2half(acc);
        if (oc < 16)
          ((__half*)outA)[(long)node2 * 16 + oc] = hv;
        else
          ((__half*)outB)[(long)node2 * 16 + (oc - 16)] = hv;
      } else if (OUT_HALF) {
        ((__half*)outA)[(long)node2 * DOUT + oc] = __float2half(acc);
      } else {
        ((float*)outA)[(long)node2 * DOUT + oc] = acc;
      }
    }
  }
}

// ---------------------------------------------------------------------------
// Host launch
// ---------------------------------------------------------------------------
static inline size_t align256(size_t v) { return (v + 255) & ~(size_t)255; }

extern "C" void kernel_launch(void* const* d_in, const int* in_sizes, int n_in,
                              void* d_out, int out_size, void* d_ws,
                              size_t ws_size, hipStream_t stream) {
  const int N = N_NODES;
  const int E = N_EDGES;
  const int RN = N_REL * N;

  const float* x = (const float*)d_in[0];
  const int* edge_index = (const int*)d_in[1];
  const int* et = (const int*)d_in[2];
  const float* W1 = (const float*)d_in[3];
  const float* root1 = (const float*)d_in[4];
  const float* b1 = (const float*)d_in[5];
  const float* W2 = (const float*)d_in[6];
  const float* root2 = (const float*)d_in[7];
  const float* b2 = (const float*)d_in[8];
  const float* W3 = (const float*)d_in[9];
  const float* root3 = (const float*)d_in[10];
  const float* b3 = (const float*)d_in[11];

  const int* src = edge_index;      // edge_index[0]
  const int* dst = edge_index + E;  // edge_index[1]

  // Workspace carve-up (~77 MB)
  char* ws = (char*)d_ws;
  size_t o = 0;
  int* cnt = (int*)(ws + o);
  o = align256(o + (size_t)RN * 4);
  int* off = (int*)(ws + o);
  o = align256(o + (size_t)RN * 4);
  int* cur = (int*)(ws + o);
  o = align256(o + (size_t)RN * 4);
  int* top = (int*)(ws + o);
  o = align256(o + 256);
  int* eidx = (int*)(ws + o);
  o = align256(o + (size_t)E * 4);
  __half* xh = (__half*)(ws + o);
  o = align256(o + (size_t)N * 16 * 2);
  __half* h1 = (__half*)(ws + o);
  o = align256(o + (size_t)N * 16 * 2);
  __half* h2lo = (__half*)(ws + o);
  o = align256(o + (size_t)N * 16 * 2);
  __half* h2hi = (__half*)(ws + o);
  o = align256(o + (size_t)N * 16 * 2);
  __half* xe = (__half*)(ws + o);
  o = align256(o + (size_t)E * 16 * 2);  // 51.2 MB, reused by all 4 passes
  (void)ws_size;

  float* out = (float*)d_out;

  const int gridE = (E + 255) / 256;        // 6250
  const int gridX = (2 * E + 255) / 256;    // 12500 (expand)
  const int gridR = (N + 31) / 32;          // 3125  (reduce)

  // --- CSR build + fp16 conversion of x ---
  hipMemsetAsync(cnt, 0, (size_t)RN * 4, stream);
  hipMemsetAsync(top, 0, 256, stream);
  cvt_kernel<<<(N * 16 / 4 + 255) / 256, 256, 0, stream>>>(x, xh, N * 16 / 4);
  count_kernel<<<gridE, 256, 0, stream>>>(dst, et, cnt, E, N);
  alloc_kernel<<<(RN + 255) / 256, 256, 0, stream>>>(cnt, off, cur, top, RN);
  fill_kernel<<<gridE, 256, 0, stream>>>(src, dst, et, cur, eidx, E, N);

  // --- layer 1: 16 -> 16, relu, fp16 out ---
  expand_kernel<<<gridX, 256, 0, stream>>>(xh, eidx, xe, E);
  reduce_kernel<16, true, false, false, true><<<gridR, 256, 0, stream>>>(
      xh, xe, cnt, off, W1, 16 * 16, root1, b1, h1, nullptr, N);

  // --- layer 2: 16 -> 32, relu, fp16 split out ---
  expand_kernel<<<gridX, 256, 0, stream>>>(h1, eidx, xe, E);
  reduce_kernel<32, true, false, true, true><<<gridR, 256, 0, stream>>>(
      h1, xe, cnt, off, W2, 16 * 32, root2, b2, h2lo, h2hi, N);

  // --- layer 3: 32 -> 64, no relu, fp32 out; two half-passes ---
  // lo half: k = 0..15
  expand_kernel<<<gridX, 256, 0, stream>>>(h2lo, eidx, xe, E);
  reduce_kernel<64, false, false, false, false><<<gridR, 256, 0, stream>>>(
      h2lo, xe, cnt, off, W3, 32 * 64, root3, b3, out, nullptr, N);
  // hi half: k = 16..31 (accumulate into out)
  expand_kernel<<<gridX, 256, 0, stream>>>(h2hi, eidx, xe, E);
  reduce_kernel<64, false, true, false, false><<<gridR, 256, 0, stream>>>(
      h2hi, xe, cnt, off, W3 + 16 * 64, 32 * 64, root3 + 16 * 64, nullptr, out,
      nullptr, N);
}